// Round 1
// baseline (9786.977 us; speedup 1.0000x reference)
//
#include <hip/hip_runtime.h>
#include <math.h>

#define V_  32000
#define C_  1024
#define L_  2
#define H_  16
#define N_  64
#define B_  2
#define T_  1024
#define FF_ 4096
#define DW_ 64
#define DA_ 64
#define DV_ 32
#define DG_ 128
#define BT_  (B_*T_)
#define BTC_ (BT_*C_)

__device__ __forceinline__ float sigf(float x){ return 1.0f/(1.0f+expf(-x)); }

// ---------------- embedding ----------------
__global__ void k_embed(const int* __restrict__ idx, const float* __restrict__ emb,
                        float* __restrict__ x){
  int i = blockIdx.x*256 + threadIdx.x;
  if (i >= BTC_) return;
  int row = i / C_, c = i - row*C_;
  x[i] = emb[(size_t)idx[row]*C_ + c];
}

// ---------------- layernorm (row-wise over C) ----------------
__global__ void k_ln(const float* __restrict__ x, const float* __restrict__ g,
                     const float* __restrict__ b, float* __restrict__ out){
  int row = blockIdx.x;
  const float* xr = x + (size_t)row*C_;
  float s = 0.f, s2 = 0.f;
  for (int c = threadIdx.x; c < C_; c += 256){ float v = xr[c]; s += v; s2 += v*v; }
  for (int o = 32; o > 0; o >>= 1){ s += __shfl_xor(s,o); s2 += __shfl_xor(s2,o); }
  __shared__ float w1s[4], w2s[4];
  int wid = threadIdx.x >> 6, lane = threadIdx.x & 63;
  if (lane == 0){ w1s[wid] = s; w2s[wid] = s2; }
  __syncthreads();
  if (threadIdx.x == 0){
    float a = 0.f, bb = 0.f;
    for (int i = 0; i < 4; i++){ a += w1s[i]; bb += w2s[i]; }
    w1s[0] = a; w2s[0] = bb;
  }
  __syncthreads();
  float mean = w1s[0] * (1.0f/C_);
  float var  = w2s[0] * (1.0f/C_) - mean*mean;
  float r = rsqrtf(var + 1e-5f);
  float* orow = out + (size_t)row*C_;
  for (int c = threadIdx.x; c < C_; c += 256)
    orow[c] = (xr[c]-mean)*r*g[c] + b[c];
}

// ---------------- time shift diff: xx = shift(xin) - xin ----------------
__global__ void k_shiftdiff(const float* __restrict__ xin, float* __restrict__ xx){
  int i = blockIdx.x*256 + threadIdx.x;
  if (i >= BTC_) return;
  int bt = i / C_;
  int t = bt % T_;
  float prev = (t > 0) ? xin[i - C_] : 0.f;
  xx[i] = prev - xin[i];
}

// ---------------- FFN token mix: kx = xc + (shift(xc)-xc)*xk[c] ----------------
__global__ void k_ffnmix(const float* __restrict__ xc, const float* __restrict__ fxk,
                         float* __restrict__ kx){
  int i = blockIdx.x*256 + threadIdx.x;
  if (i >= BTC_) return;
  int bt = i / C_, c = i - bt*C_;
  int t = bt % T_;
  float cur = xc[i];
  float prev = (t > 0) ? xc[i - C_] : 0.f;
  kx[i] = cur + (prev - cur)*fxk[c];
}

// ---------------- decay: wd = sigmoid(w0+wd)*exp(-0.5)  (== exp(w)) ----------------
__global__ void k_decay(const float* __restrict__ w0, float* __restrict__ wd){
  int i = blockIdx.x*256 + threadIdx.x;
  if (i >= BTC_) return;
  int c = i % C_;
  wd[i] = sigf(w0[c] + wd[i]) * 0.60653065971263342f;
}

// ---------------- a = sigmoid(a0 + a) ----------------
__global__ void k_asig(const float* __restrict__ a0, float* __restrict__ a){
  int i = blockIdx.x*256 + threadIdx.x;
  if (i >= BTC_) return;
  int c = i % C_;
  a[i] = sigf(a0[c] + a[i]);
}

// ---------------- v = v + (v_first - v)*sigmoid(v0 + vv) ----------------
__global__ void k_vmix(const float* __restrict__ v0, const float* __restrict__ vv,
                       const float* __restrict__ vf, float* __restrict__ v){
  int i = blockIdx.x*256 + threadIdx.x;
  if (i >= BTC_) return;
  int c = i % C_;
  float s = sigf(v0[c] + vv[i]);
  v[i] = v[i] + (vf[i] - v[i])*s;
}

// ---------------- kk normalize + k2 (in-place on k) ----------------
// grid: BT*H blocks of 64 threads
__global__ void k_kk(const float* __restrict__ kkw, const float* __restrict__ kaw,
                     const float* __restrict__ a, float* __restrict__ k,
                     float* __restrict__ kk){
  int bth = blockIdx.x;
  int lane = threadIdx.x;
  int bt = bth / H_, h = bth - bt*H_;
  int cix = h*N_ + lane;
  size_t gi = (size_t)bt*C_ + cix;
  float kv = k[gi];
  float kkv = kv * kkw[cix];
  float ss = kkv*kkv;
  for (int o = 32; o > 0; o >>= 1) ss += __shfl_xor(ss,o);
  float nrm = fmaxf(sqrtf(ss), 1e-12f);
  kk[gi] = kkv / nrm;
  float av = a[gi];
  k[gi] = kv * (1.f + (av - 1.f)*kaw[cix]);
}

// ---------------- RWKV7 scan: one block per (b,h), 256 threads ----------------
// thread (irow, jq): row irow (0..63) of S, columns jq*16..jq*16+15 in registers
__global__ __launch_bounds__(256) void k_scan(
    const float* __restrict__ r, const float* __restrict__ k2,
    const float* __restrict__ v, const float* __restrict__ wd,
    const float* __restrict__ kk, const float* __restrict__ a,
    const float* __restrict__ S0, float* __restrict__ y){
  int bh = blockIdx.x;
  int b = bh / H_, h = bh - b*H_;
  int tid = threadIdx.x;
  int irow = tid >> 2, jq = tid & 3, j0 = jq*16;
  float S[16];
#pragma unroll
  for (int jj = 0; jj < 16; jj++) S[jj] = S0[((size_t)h*N_ + irow)*N_ + j0 + jj];
  __shared__ float lr[64], lk[64], lv[64], ld[64], lkk[64], la[64];
  size_t off = ((size_t)b*T_)*C_ + h*N_;
  for (int t = 0; t < T_; t++, off += C_){
    for (int u = tid; u < 384; u += 256){
      int vec = u >> 6, n = u & 63;
      switch (vec){
        case 0: lr[n]  = r[off+n];  break;
        case 1: lk[n]  = k2[off+n]; break;
        case 2: lv[n]  = v[off+n];  break;
        case 3: ld[n]  = wd[off+n]; break;
        case 4: lkk[n] = kk[off+n]; break;
        case 5: la[n]  = a[off+n];  break;
      }
    }
    __syncthreads();
    float sa = 0.f;
#pragma unroll
    for (int jj = 0; jj < 16; jj++) sa -= S[jj]*lkk[j0+jj];  // a_ = -kk
    sa += __shfl_xor(sa,1); sa += __shfl_xor(sa,2);
    float vi = lv[irow];
    float yv = 0.f;
#pragma unroll
    for (int jj = 0; jj < 16; jj++){
      int j = j0 + jj;
      float s = S[jj]*ld[j] + sa*(lkk[j]*la[j]) + vi*lk[j];  // b_ = kk*a
      S[jj] = s;
      yv += s*lr[j];
    }
    yv += __shfl_xor(yv,1); yv += __shfl_xor(yv,2);
    if (jq == 0) y[off + irow] = yv;
    __syncthreads();
  }
}

// ---------------- groupnorm (per head, eps 64e-5) + bonus + *g, in-place on y ----------------
// grid: BT*H blocks of 64 threads
__global__ void k_gnb(const float* __restrict__ lxg, const float* __restrict__ lxb,
                      const float* __restrict__ rk, const float* __restrict__ r,
                      const float* __restrict__ k2, const float* __restrict__ v,
                      const float* __restrict__ g, float* __restrict__ y){
  int bth = blockIdx.x;
  int lane = threadIdx.x;
  int bt = bth / H_, h = bth - bt*H_;
  int cix = h*N_ + lane;
  size_t gi = (size_t)bt*C_ + cix;
  float yv = y[gi];
  float s = yv;
  for (int o = 32; o > 0; o >>= 1) s += __shfl_xor(s,o);
  float mean = s * (1.0f/N_);
  float d = yv - mean;
  float s2 = d*d;
  for (int o = 32; o > 0; o >>= 1) s2 += __shfl_xor(s2,o);
  float var = s2 * (1.0f/N_);
  float yn = d * rsqrtf(var + 64e-5f) * lxg[cix] + lxb[cix];
  float dv = r[gi]*k2[gi]*rk[h*N_ + lane];
  for (int o = 32; o > 0; o >>= 1) dv += __shfl_xor(dv,o);
  y[gi] = (yn + dv*v[gi]) * g[gi];
}

// ---------------- generic fp32 GEMM: C = epilogue(Aeff @ B) ----------------
// Aeff[m][k] = A[m][k] (+ A2[m][k]*mixv[k] if amode==1)
// ep: 0=store 1=add 2=tanh 3=sigmoid 4=relu^2
#define TS 64
#define KS 16
__global__ __launch_bounds__(256) void k_gemm(
    const float* __restrict__ A, const float* __restrict__ A2,
    const float* __restrict__ mixv, const float* __restrict__ Bm,
    float* __restrict__ Cm, int M, int K, int Nn, int amode, int ep){
  __shared__ float As[KS][TS+4];
  __shared__ float Bs[KS][TS+4];
  int n0 = blockIdx.x*TS, m0 = blockIdx.y*TS;
  int tid = threadIdx.x;
  int tx = tid & 15, ty = tid >> 4;
  float acc[4][4] = {{0.f}};
  for (int k0 = 0; k0 < K; k0 += KS){
#pragma unroll
    for (int it = 0; it < 4; it++){
      int idx = tid + 256*it;
      int ml = idx >> 4, kl = idx & 15;
      int gm = m0 + ml, gk = k0 + kl;
      float av = 0.f;
      if (gm < M){
        size_t ai = (size_t)gm*K + gk;
        av = A[ai];
        if (amode == 1) av += A2[ai]*mixv[gk];
      }
      As[kl][ml] = av;
    }
#pragma unroll
    for (int it = 0; it < 4; it++){
      int idx = tid + 256*it;
      int kl = idx >> 6, nl = idx & 63;
      int gn = n0 + nl, gk = k0 + kl;
      float bv = 0.f;
      if (gn < Nn) bv = Bm[(size_t)gk*Nn + gn];
      Bs[kl][nl] = bv;
    }
    __syncthreads();
#pragma unroll
    for (int kk = 0; kk < KS; kk++){
      float av[4], bv[4];
#pragma unroll
      for (int i = 0; i < 4; i++) av[i] = As[kk][ty*4+i];
#pragma unroll
      for (int j = 0; j < 4; j++) bv[j] = Bs[kk][tx*4+j];
#pragma unroll
      for (int i = 0; i < 4; i++)
#pragma unroll
        for (int j = 0; j < 4; j++)
          acc[i][j] += av[i]*bv[j];
    }
    __syncthreads();
  }
#pragma unroll
  for (int i = 0; i < 4; i++){
    int gm = m0 + ty*4 + i;
    if (gm >= M) continue;
#pragma unroll
    for (int j = 0; j < 4; j++){
      int gn = n0 + tx*4 + j;
      if (gn >= Nn) continue;
      size_t ci = (size_t)gm*Nn + gn;
      float vv = acc[i][j];
      switch (ep){
        case 0: Cm[ci] = vv; break;
        case 1: Cm[ci] += vv; break;
        case 2: Cm[ci] = tanhf(vv); break;
        case 3: Cm[ci] = sigf(vv); break;
        case 4: { float rr = fmaxf(vv, 0.f); Cm[ci] = rr*rr; } break;
      }
    }
  }
}

extern "C" void kernel_launch(void* const* d_in, const int* in_sizes, int n_in,
                              void* d_out, int out_size, void* d_ws, size_t ws_size,
                              hipStream_t stream){
  const int*   idx     = (const int*)  d_in[0];
  const float* emb_w   = (const float*)d_in[1];
  const float* ln0_g   = (const float*)d_in[2];
  const float* ln0_b   = (const float*)d_in[3];
  const float* ln1_g   = (const float*)d_in[4];
  const float* ln1_b   = (const float*)d_in[5];
  const float* ln2_g   = (const float*)d_in[6];
  const float* ln2_b   = (const float*)d_in[7];
  const float* lnx_g   = (const float*)d_in[8];
  const float* lnx_b   = (const float*)d_in[9];
  const float* lnout_g = (const float*)d_in[10];
  const float* lnout_b = (const float*)d_in[11];
  const float* x_mix   = (const float*)d_in[12];
  const float* w0      = (const float*)d_in[13];
  const float* w1      = (const float*)d_in[14];
  const float* w2      = (const float*)d_in[15];
  const float* a0      = (const float*)d_in[16];
  const float* a1      = (const float*)d_in[17];
  const float* a2      = (const float*)d_in[18];
  const float* v0      = (const float*)d_in[19];
  const float* v1      = (const float*)d_in[20];
  const float* v2      = (const float*)d_in[21];
  const float* g1      = (const float*)d_in[22];
  const float* g2      = (const float*)d_in[23];
  const float* k_k     = (const float*)d_in[24];
  const float* k_a     = (const float*)d_in[25];
  const float* r_k     = (const float*)d_in[26];
  const float* Wr      = (const float*)d_in[27];
  const float* Wk      = (const float*)d_in[28];
  const float* Wv      = (const float*)d_in[29];
  const float* Wo      = (const float*)d_in[30];
  const float* ffn_xk  = (const float*)d_in[31];
  const float* ffn_k   = (const float*)d_in[32];
  const float* ffn_v   = (const float*)d_in[33];
  const float* tstate  = (const float*)d_in[34];
  const float* head_w  = (const float*)d_in[35];
  float* out = (float*)d_out;

  // workspace layout (floats); total 13*BTC = ~104 MB
  float* ws     = (float*)d_ws;
  float* x      = ws;
  float* vfirst = ws + 1*(size_t)BTC_;
  float* xin    = ws + 2*(size_t)BTC_;
  float* xx     = ws + 3*(size_t)BTC_;
  float* rb     = ws + 4*(size_t)BTC_;
  float* wdec   = ws + 5*(size_t)BTC_;
  float* kb     = ws + 6*(size_t)BTC_;
  float* vb     = ws + 7*(size_t)BTC_;
  float* ab     = ws + 8*(size_t)BTC_;
  float* gb     = ws + 9*(size_t)BTC_;
  float* kkb    = ws + 10*(size_t)BTC_;
  float* yb     = ws + 11*(size_t)BTC_;
  float* tmp    = ws + 12*(size_t)BTC_;
  float* tmp_w  = tmp;                 // BT*DW
  float* tmp_a  = tmp + (size_t)BT_*64;
  float* tmp_v  = tmp + (size_t)BT_*128;
  float* tmp_g  = tmp + (size_t)BT_*192; // BT*DG
  float* hid    = rb;                  // aliases rb..vb (4*BTC = BT*FF), dead by FFN time

  dim3 blk(256);
  int ewg = (BTC_ + 255)/256;
  dim3 gCC(C_/64, BT_/64);     // (16,32)
  dim3 gFF(FF_/64, BT_/64);    // (64,32)
  dim3 gHD(V_/64, BT_/64);     // (500,32)
  dim3 gD64(1, BT_/64);
  dim3 gD128(2, BT_/64);

  k_embed<<<ewg, blk, 0, stream>>>(idx, emb_w, x);

  for (int l = 0; l < L_; l++){
    const float* mixl = x_mix + ((size_t)l*6)*C_;
    if (l == 0)
      k_ln<<<BT_, blk, 0, stream>>>(x, ln0_g, ln0_b, x);
    k_ln<<<BT_, blk, 0, stream>>>(x, ln1_g + l*C_, ln1_b + l*C_, xin);
    k_shiftdiff<<<ewg, blk, 0, stream>>>(xin, xx);

    // projections with fused token-shift mix
    k_gemm<<<gCC,  blk, 0, stream>>>(xin, xx, mixl + 0*C_, Wr + (size_t)l*C_*C_, rb,   BT_, C_, C_,  1, 0);
    k_gemm<<<gD64, blk, 0, stream>>>(xin, xx, mixl + 1*C_, w1 + (size_t)l*C_*DW_, tmp_w, BT_, C_, DW_, 1, 2); // tanh
    k_gemm<<<gCC,  blk, 0, stream>>>(xin, xx, mixl + 2*C_, Wk + (size_t)l*C_*C_, kb,   BT_, C_, C_,  1, 0);
    k_gemm<<<gCC,  blk, 0, stream>>>(xin, xx, mixl + 3*C_, Wv + (size_t)l*C_*C_, vb,   BT_, C_, C_,  1, 0);
    if (l > 0)
      k_gemm<<<gD64, blk, 0, stream>>>(xin, xx, mixl + 3*C_, v1 + (size_t)l*C_*DV_, tmp_v, BT_, C_, DV_, 1, 0);
    k_gemm<<<gD64,  blk, 0, stream>>>(xin, xx, mixl + 4*C_, a1 + (size_t)l*C_*DA_, tmp_a, BT_, C_, DA_, 1, 0);
    k_gemm<<<gD128, blk, 0, stream>>>(xin, xx, mixl + 5*C_, g1 + (size_t)l*C_*DG_, tmp_g, BT_, C_, DG_, 1, 3); // sigmoid

    // w path: wdec = exp(w)
    k_gemm<<<gCC, blk, 0, stream>>>(tmp_w, nullptr, nullptr, w2 + (size_t)l*DW_*C_, wdec, BT_, DW_, C_, 0, 0);
    k_decay<<<ewg, blk, 0, stream>>>(w0 + l*C_, wdec);
    // a path
    k_gemm<<<gCC, blk, 0, stream>>>(tmp_a, nullptr, nullptr, a2 + (size_t)l*DA_*C_, ab, BT_, DA_, C_, 0, 0);
    k_asig<<<ewg, blk, 0, stream>>>(a0 + l*C_, ab);
    // v path
    if (l == 0){
      hipMemcpyAsync(vfirst, vb, (size_t)BTC_*sizeof(float), hipMemcpyDeviceToDevice, stream);
    } else {
      k_gemm<<<gCC, blk, 0, stream>>>(tmp_v, nullptr, nullptr, v2 + (size_t)l*DV_*C_, xin, BT_, DV_, C_, 0, 0);
      k_vmix<<<ewg, blk, 0, stream>>>(v0 + l*C_, xin, vfirst, vb);
    }
    // g path
    k_gemm<<<gCC, blk, 0, stream>>>(tmp_g, nullptr, nullptr, g2 + (size_t)l*DG_*C_, gb, BT_, DG_, C_, 0, 0);

    // kk normalize + k2 (k2 in-place in kb)
    k_kk<<<BT_*H_, 64, 0, stream>>>(k_k + l*C_, k_a + l*C_, ab, kb, kkb);

    // sequential state scan
    k_scan<<<B_*H_, 256, 0, stream>>>(rb, kb, vb, wdec, kkb, ab,
                                      tstate + (size_t)l*H_*N_*N_, yb);

    // groupnorm + bonus + *g (in-place on yb)
    k_gnb<<<BT_*H_, 64, 0, stream>>>(lnx_g + l*C_, lnx_b + l*C_, r_k + (size_t)l*H_*N_,
                                     rb, kb, vb, gb, yb);

    // x += (y*g) @ Wo
    k_gemm<<<gCC, blk, 0, stream>>>(yb, nullptr, nullptr, Wo + (size_t)l*C_*C_, x, BT_, C_, C_, 0, 1);

    // FFN
    k_ln<<<BT_, blk, 0, stream>>>(x, ln2_g + l*C_, ln2_b + l*C_, xin);
    k_ffnmix<<<ewg, blk, 0, stream>>>(xin, ffn_xk + l*C_, xx);
    k_gemm<<<gFF, blk, 0, stream>>>(xx, nullptr, nullptr, ffn_k + (size_t)l*C_*FF_, hid, BT_, C_, FF_, 0, 4); // relu^2
    k_gemm<<<gCC, blk, 0, stream>>>(hid, nullptr, nullptr, ffn_v + (size_t)l*FF_*C_, x, BT_, FF_, C_, 0, 1);
  }

  // head
  k_ln<<<BT_, blk, 0, stream>>>(x, lnout_g, lnout_b, xin);
  k_gemm<<<gHD, blk, 0, stream>>>(xin, nullptr, nullptr, head_w, out, BT_, C_, V_, 0, 0);
}

// Round 2
// 4548.304 us; speedup vs baseline: 2.1518x; 2.1518x over previous
//
#include <hip/hip_runtime.h>
#include <hip/hip_bf16.h>
#include <math.h>

#define V_  32000
#define C_  1024
#define L_  2
#define H_  16
#define N_  64
#define B_  2
#define T_  1024
#define FF_ 4096
#define DW_ 64
#define DA_ 64
#define DV_ 32
#define DG_ 128
#define BT_  (B_*T_)
#define BTC_ (BT_*C_)

typedef float floatx4 __attribute__((ext_vector_type(4)));
typedef short shortx8 __attribute__((ext_vector_type(8)));
typedef __attribute__((address_space(1))) unsigned int gu32;
typedef __attribute__((address_space(3))) unsigned int su32;

__device__ __forceinline__ float sigf(float x){ return 1.0f/(1.0f+expf(-x)); }
__device__ __forceinline__ unsigned short f2bf(float x){
  __hip_bfloat16 h = __float2bfloat16(x);
  return *(unsigned short*)&h;
}
__device__ __forceinline__ void gload16(const void* g, void* l){
  __builtin_amdgcn_global_load_lds((const gu32*)g, (su32*)l, 16, 0, 0);
}

// ---------------- embedding ----------------
__global__ void k_embed(const int* __restrict__ idx, const float* __restrict__ emb,
                        float* __restrict__ x){
  int i = blockIdx.x*256 + threadIdx.x;
  if (i >= BTC_) return;
  int row = i / C_, c = i - row*C_;
  x[i] = emb[(size_t)idx[row]*C_ + c];
}

// ---------------- layernorm (row-wise over C) ----------------
__global__ void k_ln(const float* __restrict__ x, const float* __restrict__ g,
                     const float* __restrict__ b, float* __restrict__ out){
  int row = blockIdx.x;
  const float* xr = x + (size_t)row*C_;
  float s = 0.f, s2 = 0.f;
  for (int c = threadIdx.x; c < C_; c += 256){ float v = xr[c]; s += v; s2 += v*v; }
  for (int o = 32; o > 0; o >>= 1){ s += __shfl_xor(s,o); s2 += __shfl_xor(s2,o); }
  __shared__ float w1s[4], w2s[4];
  int wid = threadIdx.x >> 6, lane = threadIdx.x & 63;
  if (lane == 0){ w1s[wid] = s; w2s[wid] = s2; }
  __syncthreads();
  if (threadIdx.x == 0){
    float a = 0.f, bb = 0.f;
    for (int i = 0; i < 4; i++){ a += w1s[i]; bb += w2s[i]; }
    w1s[0] = a; w2s[0] = bb;
  }
  __syncthreads();
  float mean = w1s[0] * (1.0f/C_);
  float var  = w2s[0] * (1.0f/C_) - mean*mean;
  float r = rsqrtf(var + 1e-5f);
  float* orow = out + (size_t)row*C_;
  for (int c = threadIdx.x; c < C_; c += 256)
    orow[c] = (xr[c]-mean)*r*g[c] + b[c];
}

// ---------------- mix6: writes 6 bf16 mixed matrices ----------------
__global__ void k_mix6(const float* __restrict__ xin, const float* __restrict__ mixl,
                       unsigned short* __restrict__ m6){
  int i = blockIdx.x*256 + threadIdx.x;
  if (i >= BTC_) return;
  int bt = i / C_, c = i - bt*C_;
  int t = bt % T_;
  float cur = xin[i];
  float prev = (t > 0) ? xin[i - C_] : 0.f;
  float d = prev - cur;
#pragma unroll
  for (int j = 0; j < 6; j++)
    m6[(size_t)j*BTC_ + i] = f2bf(cur + d*mixl[j*C_ + c]);
}

// ---------------- FFN token mix -> bf16 ----------------
__global__ void k_ffnmix(const float* __restrict__ xc, const float* __restrict__ fxk,
                         unsigned short* __restrict__ kx){
  int i = blockIdx.x*256 + threadIdx.x;
  if (i >= BTC_) return;
  int bt = i / C_, c = i - bt*C_;
  int t = bt % T_;
  float cur = xc[i];
  float prev = (t > 0) ? xc[i - C_] : 0.f;
  kx[i] = f2bf(cur + (prev - cur)*fxk[c]);
}

// ---------------- cast fp32 -> bf16 ----------------
__global__ void k_cast16(const float* __restrict__ in, unsigned short* __restrict__ out){
  int i = blockIdx.x*256 + threadIdx.x;
  if (i >= BTC_) return;
  out[i] = f2bf(in[i]);
}

// ---------------- decay: wd = sigmoid(w0+wd)*exp(-0.5)  (== exp(w)) ----------------
__global__ void k_decay(const float* __restrict__ w0, float* __restrict__ wd){
  int i = blockIdx.x*256 + threadIdx.x;
  if (i >= BTC_) return;
  int c = i % C_;
  wd[i] = sigf(w0[c] + wd[i]) * 0.60653065971263342f;
}

// ---------------- a = sigmoid(a0 + a) ----------------
__global__ void k_asig(const float* __restrict__ a0, float* __restrict__ a){
  int i = blockIdx.x*256 + threadIdx.x;
  if (i >= BTC_) return;
  int c = i % C_;
  a[i] = sigf(a0[c] + a[i]);
}

// ---------------- v = v + (v_first - v)*sigmoid(v0 + vv) ----------------
__global__ void k_vmix(const float* __restrict__ v0, const float* __restrict__ vv,
                       const float* __restrict__ vf, float* __restrict__ v){
  int i = blockIdx.x*256 + threadIdx.x;
  if (i >= BTC_) return;
  int c = i % C_;
  float s = sigf(v0[c] + vv[i]);
  v[i] = v[i] + (vf[i] - v[i])*s;
}

// ---------------- kk normalize + k2 (in-place on k) ----------------
__global__ void k_kk(const float* __restrict__ kkw, const float* __restrict__ kaw,
                     const float* __restrict__ a, float* __restrict__ k,
                     float* __restrict__ kk){
  int bth = blockIdx.x;
  int lane = threadIdx.x;
  int bt = bth / H_, h = bth - bt*H_;
  int cix = h*N_ + lane;
  size_t gi = (size_t)bt*C_ + cix;
  float kv = k[gi];
  float kkv = kv * kkw[cix];
  float ss = kkv*kkv;
  for (int o = 32; o > 0; o >>= 1) ss += __shfl_xor(ss,o);
  float nrm = fmaxf(sqrtf(ss), 1e-12f);
  kk[gi] = kkv / nrm;
  float av = a[gi];
  k[gi] = kv * (1.f + (av - 1.f)*kaw[cix]);
}

// ---------------- RWKV7 scan: one block per (b,h), 256 threads ----------------
__global__ __launch_bounds__(256) void k_scan(
    const float* __restrict__ r, const float* __restrict__ k2,
    const float* __restrict__ v, const float* __restrict__ wd,
    const float* __restrict__ kk, const float* __restrict__ a,
    const float* __restrict__ S0, float* __restrict__ y){
  int bh = blockIdx.x;
  int b = bh / H_, h = bh - b*H_;
  int tid = threadIdx.x;
  int irow = tid >> 2, jq = tid & 3, j0 = jq*16;
  float S[16];
#pragma unroll
  for (int jj = 0; jj < 16; jj++) S[jj] = S0[((size_t)h*N_ + irow)*N_ + j0 + jj];
  __shared__ float lr[64], lk[64], lv[64], ld[64], lkk[64], la[64];
  size_t off = ((size_t)b*T_)*C_ + h*N_;
  for (int t = 0; t < T_; t++, off += C_){
    for (int u = tid; u < 384; u += 256){
      int vec = u >> 6, n = u & 63;
      switch (vec){
        case 0: lr[n]  = r[off+n];  break;
        case 1: lk[n]  = k2[off+n]; break;
        case 2: lv[n]  = v[off+n];  break;
        case 3: ld[n]  = wd[off+n]; break;
        case 4: lkk[n] = kk[off+n]; break;
        case 5: la[n]  = a[off+n];  break;
      }
    }
    __syncthreads();
    float sa = 0.f;
#pragma unroll
    for (int jj = 0; jj < 16; jj++) sa -= S[jj]*lkk[j0+jj];  // a_ = -kk
    sa += __shfl_xor(sa,1); sa += __shfl_xor(sa,2);
    float vi = lv[irow];
    float yv = 0.f;
#pragma unroll
    for (int jj = 0; jj < 16; jj++){
      int j = j0 + jj;
      float s = S[jj]*ld[j] + sa*(lkk[j]*la[j]) + vi*lk[j];  // b_ = kk*a
      S[jj] = s;
      yv += s*lr[j];
    }
    yv += __shfl_xor(yv,1); yv += __shfl_xor(yv,2);
    if (jq == 0) y[off + irow] = yv;
    __syncthreads();
  }
}

// ---------------- groupnorm + bonus + *g -> bf16 ----------------
__global__ void k_gnb(const float* __restrict__ lxg, const float* __restrict__ lxb,
                      const float* __restrict__ rk, const float* __restrict__ r,
                      const float* __restrict__ k2, const float* __restrict__ v,
                      const float* __restrict__ g, const float* __restrict__ y,
                      unsigned short* __restrict__ yg){
  int bth = blockIdx.x;
  int lane = threadIdx.x;
  int bt = bth / H_, h = bth - bt*H_;
  int cix = h*N_ + lane;
  size_t gi = (size_t)bt*C_ + cix;
  float yv = y[gi];
  float s = yv;
  for (int o = 32; o > 0; o >>= 1) s += __shfl_xor(s,o);
  float mean = s * (1.0f/N_);
  float d = yv - mean;
  float s2 = d*d;
  for (int o = 32; o > 0; o >>= 1) s2 += __shfl_xor(s2,o);
  float var = s2 * (1.0f/N_);
  float yn = d * rsqrtf(var + 64e-5f) * lxg[cix] + lxb[cix];
  float dv = r[gi]*k2[gi]*rk[h*N_ + lane];
  for (int o = 32; o > 0; o >>= 1) dv += __shfl_xor(dv,o);
  yg[gi] = f2bf((yn + dv*v[gi]) * g[gi]);
}

// ---------------- weight transpose + fp32->bf16: in [R][Cc] -> out [Cpad][R] ----------------
__global__ void k_tc(const float* __restrict__ in, unsigned short* __restrict__ out,
                     int R, int Cc, int Cpad){
  __shared__ float t[32][33];
  int c0 = blockIdx.x*32, r0 = blockIdx.y*32;
  int tx = threadIdx.x, ty = threadIdx.y;
  for (int i = ty; i < 32; i += 8){
    int r = r0+i, c = c0+tx;
    t[i][tx] = (r < R && c < Cc) ? in[(size_t)r*Cc + c] : 0.f;
  }
  __syncthreads();
  for (int i = ty; i < 32; i += 8){
    int oc = c0+i, orr = r0+tx;
    if (oc < Cpad && orr < R) out[(size_t)oc*R + orr] = f2bf(t[tx][i]);
  }
}

// ---------------- bf16 MFMA GEMM: C = ep(A[M][K](lda) @ Bt[N][K]^T) ----------------
// tile 128x128, BK=32, 4 waves each own a 64x64 quadrant (4x4 MFMA 16x16x32 tiles)
// ep: 0=store f32, 1=add f32, 2=bf16, 3=tanh->bf16, 4=sigmoid->bf16, 5=relu^2->bf16
__global__ __launch_bounds__(256) void k_mgemm(
    const short* __restrict__ A, int lda, const short* __restrict__ Bt,
    float* __restrict__ Cf, unsigned short* __restrict__ Cb, int ldc,
    int K, int ep){
  __shared__ __attribute__((aligned(16))) short As[128*32];
  __shared__ __attribute__((aligned(16))) short Bs[128*32];
  int m0 = blockIdx.y*128, n0 = blockIdx.x*128;
  int tid = threadIdx.x, wave = tid >> 6, lane = tid & 63;
  int lhi = lane >> 4, llo = lane & 15;
  int wm = wave & 1, wn = wave >> 1;
  int arow = lane >> 2, acol = (lane & 3)*8;
  floatx4 acc[4][4];
#pragma unroll
  for (int i = 0; i < 4; i++)
#pragma unroll
    for (int j = 0; j < 4; j++) acc[i][j] = (floatx4){0.f,0.f,0.f,0.f};

  for (int k0 = 0; k0 < K; k0 += 32){
#pragma unroll
    for (int q = 0; q < 2; q++){
      int r0 = wave*32 + q*16;
      gload16(A  + (size_t)(m0 + r0 + arow)*lda + k0 + acol, As + r0*32);
      gload16(Bt + (size_t)(n0 + r0 + arow)*K   + k0 + acol, Bs + r0*32);
    }
    __syncthreads();
    shortx8 af[4], bfv[4];
#pragma unroll
    for (int mi = 0; mi < 4; mi++)
      af[mi] = *(const shortx8*)(As + ((wm*64 + mi*16 + llo)*32 + lhi*8));
#pragma unroll
    for (int nj = 0; nj < 4; nj++)
      bfv[nj] = *(const shortx8*)(Bs + ((wn*64 + nj*16 + llo)*32 + lhi*8));
#pragma unroll
    for (int mi = 0; mi < 4; mi++)
#pragma unroll
      for (int nj = 0; nj < 4; nj++)
        acc[mi][nj] = __builtin_amdgcn_mfma_f32_16x16x32_bf16(af[mi], bfv[nj], acc[mi][nj], 0, 0, 0);
    __syncthreads();
  }
#pragma unroll
  for (int mi = 0; mi < 4; mi++){
#pragma unroll
    for (int nj = 0; nj < 4; nj++){
      int gr0 = m0 + wm*64 + mi*16 + lhi*4;
      int gc  = n0 + wn*64 + nj*16 + llo;
#pragma unroll
      for (int rg = 0; rg < 4; rg++){
        size_t ci = (size_t)(gr0 + rg)*ldc + gc;
        float v = acc[mi][nj][rg];
        switch (ep){
          case 0: Cf[ci] = v; break;
          case 1: Cf[ci] += v; break;
          case 2: Cb[ci] = f2bf(v); break;
          case 3: Cb[ci] = f2bf(tanhf(v)); break;
          case 4: Cb[ci] = f2bf(sigf(v)); break;
          case 5: { float rr = fmaxf(v, 0.f); Cb[ci] = f2bf(rr*rr); } break;
        }
      }
    }
  }
}

extern "C" void kernel_launch(void* const* d_in, const int* in_sizes, int n_in,
                              void* d_out, int out_size, void* d_ws, size_t ws_size,
                              hipStream_t stream){
  const int*   idx     = (const int*)  d_in[0];
  const float* emb_w   = (const float*)d_in[1];
  const float* ln0_g   = (const float*)d_in[2];
  const float* ln0_b   = (const float*)d_in[3];
  const float* ln1_g   = (const float*)d_in[4];
  const float* ln1_b   = (const float*)d_in[5];
  const float* ln2_g   = (const float*)d_in[6];
  const float* ln2_b   = (const float*)d_in[7];
  const float* lnx_g   = (const float*)d_in[8];
  const float* lnx_b   = (const float*)d_in[9];
  const float* lnout_g = (const float*)d_in[10];
  const float* lnout_b = (const float*)d_in[11];
  const float* x_mix   = (const float*)d_in[12];
  const float* w0      = (const float*)d_in[13];
  const float* w1      = (const float*)d_in[14];
  const float* w2      = (const float*)d_in[15];
  const float* a0      = (const float*)d_in[16];
  const float* a1      = (const float*)d_in[17];
  const float* a2      = (const float*)d_in[18];
  const float* v0      = (const float*)d_in[19];
  const float* v1      = (const float*)d_in[20];
  const float* v2      = (const float*)d_in[21];
  const float* g1      = (const float*)d_in[22];
  const float* g2      = (const float*)d_in[23];
  const float* k_k     = (const float*)d_in[24];
  const float* k_a     = (const float*)d_in[25];
  const float* r_k     = (const float*)d_in[26];
  const float* Wr      = (const float*)d_in[27];
  const float* Wk      = (const float*)d_in[28];
  const float* Wv      = (const float*)d_in[29];
  const float* Wo      = (const float*)d_in[30];
  const float* ffn_xk  = (const float*)d_in[31];
  const float* ffn_k   = (const float*)d_in[32];
  const float* ffn_v   = (const float*)d_in[33];
  const float* tstate  = (const float*)d_in[34];
  const float* head_w  = (const float*)d_in[35];
  float* out = (float*)d_out;

  // -------- workspace carve --------
  char* p = (char*)d_ws;
  auto alloc = [&](size_t bytes)->void*{ void* r = (void*)p; p += (bytes + 255) & ~(size_t)255; return r; };
  float* x      = (float*)alloc((size_t)BTC_*4);
  float* vfirst = (float*)alloc((size_t)BTC_*4);
  float* xin    = (float*)alloc((size_t)BTC_*4);
  float* rb     = (float*)alloc((size_t)BTC_*4);
  float* wdec   = (float*)alloc((size_t)BTC_*4);
  float* kb     = (float*)alloc((size_t)BTC_*4);
  float* vb     = (float*)alloc((size_t)BTC_*4);
  float* ab     = (float*)alloc((size_t)BTC_*4);
  float* kkb    = (float*)alloc((size_t)BTC_*4);
  float* yb     = (float*)alloc((size_t)BTC_*4);
  float* gb     = (float*)alloc((size_t)BTC_*4);
  unsigned short* act16 = (unsigned short*)alloc((size_t)6*BTC_*2);
  unsigned short* m_r = act16;
  unsigned short* m_w = act16 + 1*(size_t)BTC_;
  unsigned short* m_k = act16 + 2*(size_t)BTC_;
  unsigned short* m_v = act16 + 3*(size_t)BTC_;
  unsigned short* m_a = act16 + 4*(size_t)BTC_;
  unsigned short* m_g = act16 + 5*(size_t)BTC_;
  unsigned short* yg16  = m_r;   // alias: m6 dead after projections
  unsigned short* kx16  = m_w;
  unsigned short* hid16 = m_k;   // 16MB spans m_k..m_g
  unsigned short* xh16  = m_r;
  unsigned short* w16 = (unsigned short*)alloc((size_t)BT_*128*2);
  unsigned short* a16 = (unsigned short*)alloc((size_t)BT_*128*2);
  unsigned short* v16 = (unsigned short*)alloc((size_t)BT_*128*2);
  unsigned short* g16 = (unsigned short*)alloc((size_t)BT_*128*2);
  unsigned short *WrT[L_], *WkT[L_], *WvT[L_], *WoT[L_];
  unsigned short *w1T[L_], *a1T[L_], *v1T[L_], *g1T[L_];
  unsigned short *w2T[L_], *a2T[L_], *v2T[L_], *g2T[L_];
  unsigned short *fkT[L_], *fvT[L_];
  for (int l = 0; l < L_; l++){
    WrT[l] = (unsigned short*)alloc((size_t)C_*C_*2);
    WkT[l] = (unsigned short*)alloc((size_t)C_*C_*2);
    WvT[l] = (unsigned short*)alloc((size_t)C_*C_*2);
    WoT[l] = (unsigned short*)alloc((size_t)C_*C_*2);
    w1T[l] = (unsigned short*)alloc((size_t)128*C_*2);
    a1T[l] = (unsigned short*)alloc((size_t)128*C_*2);
    v1T[l] = (unsigned short*)alloc((size_t)128*C_*2);
    g1T[l] = (unsigned short*)alloc((size_t)128*C_*2);
    w2T[l] = (unsigned short*)alloc((size_t)C_*64*2);
    a2T[l] = (unsigned short*)alloc((size_t)C_*64*2);
    v2T[l] = (unsigned short*)alloc((size_t)C_*32*2);
    g2T[l] = (unsigned short*)alloc((size_t)C_*128*2);
    fkT[l] = (unsigned short*)alloc((size_t)FF_*C_*2);
    fvT[l] = (unsigned short*)alloc((size_t)C_*FF_*2);
  }
  unsigned short* hwT = (unsigned short*)alloc((size_t)V_*C_*2);

  dim3 blk(256);
  dim3 tcb(32, 8);
  int ewg = (BTC_ + 255)/256;

  auto MG = [&](const unsigned short* A, int lda, const unsigned short* Bt,
                float* Cf, unsigned short* Cb, int ldc, int M, int Nn, int K, int ep){
    k_mgemm<<<dim3(Nn/128, M/128), 256, 0, stream>>>(
      (const short*)A, lda, (const short*)Bt, Cf, Cb, ldc, K, ep);
  };

  // -------- weight convert/transpose (per call; weights re-read fresh) --------
  for (int l = 0; l < L_; l++){
    k_tc<<<dim3(32,32), tcb, 0, stream>>>(Wr + (size_t)l*C_*C_, WrT[l], C_, C_, C_);
    k_tc<<<dim3(32,32), tcb, 0, stream>>>(Wk + (size_t)l*C_*C_, WkT[l], C_, C_, C_);
    k_tc<<<dim3(32,32), tcb, 0, stream>>>(Wv + (size_t)l*C_*C_, WvT[l], C_, C_, C_);
    k_tc<<<dim3(32,32), tcb, 0, stream>>>(Wo + (size_t)l*C_*C_, WoT[l], C_, C_, C_);
    k_tc<<<dim3(4,32),  tcb, 0, stream>>>(w1 + (size_t)l*C_*DW_, w1T[l], C_, DW_, 128);
    k_tc<<<dim3(4,32),  tcb, 0, stream>>>(a1 + (size_t)l*C_*DA_, a1T[l], C_, DA_, 128);
    k_tc<<<dim3(4,32),  tcb, 0, stream>>>(v1 + (size_t)l*C_*DV_, v1T[l], C_, DV_, 128);
    k_tc<<<dim3(4,32),  tcb, 0, stream>>>(g1 + (size_t)l*C_*DG_, g1T[l], C_, DG_, 128);
    k_tc<<<dim3(32,2),  tcb, 0, stream>>>(w2 + (size_t)l*DW_*C_, w2T[l], DW_, C_, C_);
    k_tc<<<dim3(32,2),  tcb, 0, stream>>>(a2 + (size_t)l*DA_*C_, a2T[l], DA_, C_, C_);
    k_tc<<<dim3(32,1),  tcb, 0, stream>>>(v2 + (size_t)l*DV_*C_, v2T[l], DV_, C_, C_);
    k_tc<<<dim3(32,4),  tcb, 0, stream>>>(g2 + (size_t)l*DG_*C_, g2T[l], DG_, C_, C_);
    k_tc<<<dim3(128,32),tcb, 0, stream>>>(ffn_k + (size_t)l*C_*FF_, fkT[l], C_, FF_, FF_);
    k_tc<<<dim3(32,128),tcb, 0, stream>>>(ffn_v + (size_t)l*FF_*C_, fvT[l], FF_, C_, C_);
  }
  k_tc<<<dim3(1000,32), tcb, 0, stream>>>(head_w, hwT, C_, V_, V_);

  k_embed<<<ewg, blk, 0, stream>>>(idx, emb_w, x);

  for (int l = 0; l < L_; l++){
    const float* mixl = x_mix + ((size_t)l*6)*C_;
    if (l == 0)
      k_ln<<<BT_, blk, 0, stream>>>(x, ln0_g, ln0_b, x);
    k_ln<<<BT_, blk, 0, stream>>>(x, ln1_g + l*C_, ln1_b + l*C_, xin);
    k_mix6<<<ewg, blk, 0, stream>>>(xin, mixl, act16);

    // projections (bf16 MFMA)
    MG(m_r, C_, WrT[l], rb, 0, C_, BT_, C_, C_, 0);
    MG(m_w, C_, w1T[l], 0, w16, 128, BT_, 128, C_, 3);   // tanh -> bf16
    MG(m_k, C_, WkT[l], kb, 0, C_, BT_, C_, C_, 0);
    MG(m_v, C_, WvT[l], vb, 0, C_, BT_, C_, C_, 0);
    if (l > 0)
      MG(m_v, C_, v1T[l], 0, v16, 128, BT_, 128, C_, 2);
    MG(m_a, C_, a1T[l], 0, a16, 128, BT_, 128, C_, 2);
    MG(m_g, C_, g1T[l], 0, g16, 128, BT_, 128, C_, 4);   // sigmoid -> bf16

    // second-stage low-rank
    MG(w16, 128, w2T[l], wdec, 0, C_, BT_, C_, DW_, 0);
    k_decay<<<ewg, blk, 0, stream>>>(w0 + l*C_, wdec);
    MG(a16, 128, a2T[l], ab, 0, C_, BT_, C_, DA_, 0);
    k_asig<<<ewg, blk, 0, stream>>>(a0 + l*C_, ab);
    if (l == 0){
      hipMemcpyAsync(vfirst, vb, (size_t)BTC_*4, hipMemcpyDeviceToDevice, stream);
    } else {
      MG(v16, 128, v2T[l], xin, 0, C_, BT_, C_, DV_, 0);
      k_vmix<<<ewg, blk, 0, stream>>>(v0 + l*C_, xin, vfirst, vb);
    }
    MG(g16, 128, g2T[l], gb, 0, C_, BT_, C_, DG_, 0);

    // kk normalize + k2
    k_kk<<<BT_*H_, 64, 0, stream>>>(k_k + l*C_, k_a + l*C_, ab, kb, kkb);

    // sequential scan (fp32)
    k_scan<<<B_*H_, 256, 0, stream>>>(rb, kb, vb, wdec, kkb, ab,
                                      tstate + (size_t)l*H_*N_*N_, yb);

    // groupnorm + bonus + *g -> bf16
    k_gnb<<<BT_*H_, 64, 0, stream>>>(lnx_g + l*C_, lnx_b + l*C_, r_k + (size_t)l*H_*N_,
                                     rb, kb, vb, gb, yb, yg16);

    // x += (y*g) @ Wo
    MG(yg16, C_, WoT[l], x, 0, C_, BT_, C_, C_, 1);

    // FFN
    k_ln<<<BT_, blk, 0, stream>>>(x, ln2_g + l*C_, ln2_b + l*C_, xin);
    k_ffnmix<<<ewg, blk, 0, stream>>>(xin, ffn_xk + l*C_, kx16);
    MG(kx16, C_, fkT[l], 0, hid16, FF_, BT_, FF_, C_, 5);  // relu^2 -> bf16
    MG(hid16, FF_, fvT[l], x, 0, C_, BT_, C_, FF_, 1);
  }

  // head
  k_ln<<<BT_, blk, 0, stream>>>(x, lnout_g, lnout_b, xin);
  k_cast16<<<ewg, blk, 0, stream>>>(xin, xh16);
  MG(xh16, C_, hwT, out, 0, V_, BT_, V_, C_, 0);
}